// Round 6
// baseline (421.356 us; speedup 1.0000x reference)
//
#include <hip/hip_runtime.h>
#include <hip/hip_bf16.h>

using bf16 = __hip_bfloat16;
typedef __attribute__((ext_vector_type(8))) short bf16x8;   // 8 bf16 = 4 VGPRs (MFMA A/B frag)
typedef __attribute__((ext_vector_type(4))) float f32x4;    // MFMA C/D frag

__device__ inline short bfbits(float f) {
  union { bf16 h; short s; } u;
  u.h = __float2bfloat16(f);
  return u.s;
}

// Load 8 contiguous elements at the FULLY-FORMED pointer g, return as bf16x8.
// (All address arithmetic happens at the call site, exactly once.)
__device__ inline bf16x8 ldcvt(const float* __restrict__ g) {
  const float4 f0 = *(const float4*)(g);
  const float4 f1 = *(const float4*)(g + 4);
  union { short s[8]; bf16x8 v; } u;
  u.s[0] = bfbits(f0.x); u.s[1] = bfbits(f0.y); u.s[2] = bfbits(f0.z); u.s[3] = bfbits(f0.w);
  u.s[4] = bfbits(f1.x); u.s[5] = bfbits(f1.y); u.s[6] = bfbits(f1.z); u.s[7] = bfbits(f1.w);
  return u.v;
}
__device__ inline bf16x8 ldcvt(const bf16* __restrict__ g) {
  return *(const bf16x8*)g;
}

__device__ inline void store_c(float* C, size_t idx, float v) { C[idx] = v; }
__device__ inline void store_c(bf16*  C, size_t idx, float v) { C[idx] = __float2bfloat16(v); }

// C[m,n] = sum_k A[m*lda+k] * B[n*ldb+k]  (+ bias[n], fp32, if non-null).
// A/B fp32 or bf16 (converted to bf16 during staging); bf16 MFMA, fp32 accum.
// M,N multiples of 128; K multiple of 32. Grid: (N/128, M/128), block 256.
template <typename TA, typename TB, typename TC>
__global__ __launch_bounds__(256)
void gemm_nt(const TA* __restrict__ A, const TB* __restrict__ B,
             const float* __restrict__ bias, TC* __restrict__ C,
             int K, int lda, int ldb, int ldc) {
  __shared__ __align__(16) bf16 As[128 * 32];
  __shared__ __align__(16) bf16 Bs[128 * 32];
  const int tid  = threadIdx.x;
  const int lane = tid & 63;
  const int wave = tid >> 6;          // 4 waves, 2x2 of 64x64
  const int wm = wave >> 1, wn = wave & 1;
  const int m0 = blockIdx.y * 128;
  const int n0 = blockIdx.x * 128;

  // staging: thread covers rows srow and srow+64 (16B = 8 bf16 each).
  // Pointers below are FINAL (include srow/scol); only +k0 is added in-loop.
  const int srow = tid >> 2;          // 0..63
  const int scol = (tid & 3) * 8;     // 0,8,16,24
  const TA* gA0 = A + (size_t)(m0 + srow) * lda + scol;
  const TA* gA1 = A + (size_t)(m0 + 64 + srow) * lda + scol;
  const TB* gB0 = B + (size_t)(n0 + srow) * ldb + scol;
  const TB* gB1 = B + (size_t)(n0 + 64 + srow) * ldb + scol;
  bf16* lA0 = &As[srow * 32 + scol];
  bf16* lA1 = lA0 + 64 * 32;
  bf16* lB0 = &Bs[srow * 32 + scol];
  bf16* lB1 = lB0 + 64 * 32;

  const int fr = lane & 15;           // m (A) / n (B) within 16
  const int kq = (lane >> 4) * 8;     // k offset of this lane's 8 contiguous elems
  f32x4 acc[4][4] = {};

  for (int k0 = 0; k0 < K; k0 += 32) {
    // loads (+convert) issued before the barrier so latency overlaps the wait
    const bf16x8 a0 = ldcvt(gA0 + k0);
    const bf16x8 a1 = ldcvt(gA1 + k0);
    const bf16x8 b0 = ldcvt(gB0 + k0);
    const bf16x8 b1 = ldcvt(gB1 + k0);
    __syncthreads();                  // prev iter's LDS reads done
    *(bf16x8*)lA0 = a0;
    *(bf16x8*)lA1 = a1;
    *(bf16x8*)lB0 = b0;
    *(bf16x8*)lB1 = b1;
    __syncthreads();                  // staging visible to all waves
    bf16x8 af[4], bfv[4];
#pragma unroll
    for (int t = 0; t < 4; ++t) {
      af[t]  = *(const bf16x8*)&As[(wm * 64 + t * 16 + fr) * 32 + kq];
      bfv[t] = *(const bf16x8*)&Bs[(wn * 64 + t * 16 + fr) * 32 + kq];
    }
#pragma unroll
    for (int i = 0; i < 4; ++i)
#pragma unroll
      for (int j = 0; j < 4; ++j)
        acc[i][j] = __builtin_amdgcn_mfma_f32_16x16x32_bf16(af[i], bfv[j], acc[i][j], 0, 0, 0);
  }

  // C/D layout (verified m89/m91): col = lane&15, row = (lane>>4)*4 + r
  const int rq  = (lane >> 4) * 4;
  const int col = lane & 15;
#pragma unroll
  for (int j = 0; j < 4; ++j) {
    const int cn = n0 + wn * 64 + j * 16 + col;
    const float bv = bias ? bias[cn] : 0.0f;
#pragma unroll
    for (int i = 0; i < 4; ++i) {
      const int cm = m0 + wm * 64 + i * 16 + rq;
#pragma unroll
      for (int r = 0; r < 4; ++r)
        store_c(C, (size_t)(cm + r) * ldc + cn, acc[i][j][r] + bv);
    }
  }
}

// Per-token head-attention on the bf16 qkv workspace.
// qkv row = [q(16x64) | k(16x64) | v(16x64)]. One wave per token. attn -> q slot.
__global__ __launch_bounds__(256)
void attn_heads(bf16* __restrict__ qkv) {
  __shared__ __align__(16) bf16  s_qkv[4][3072];
  __shared__ __align__(16) float s_w[4][256];
  const int lane = threadIdx.x & 63;
  const int wave = threadIdx.x >> 6;
  const size_t tok = (size_t)blockIdx.x * 4 + wave;
  bf16* grow = qkv + tok * 3072;

#pragma unroll
  for (int i = 0; i < 6; ++i) {
    const int off = (i * 64 + lane) * 8;
    *(uint4*)(&s_qkv[wave][off]) = *(const uint4*)(&grow[off]);
  }
  __syncthreads();

  const bf16* sq = s_qkv[wave];
  const int fr   = lane & 15;
  const int quad = lane >> 4;

  // scores = q @ k^T via 2 MFMAs (K=64 -> 2 chunks of 32)
  f32x4 sc = {0.f, 0.f, 0.f, 0.f};
#pragma unroll
  for (int c = 0; c < 2; ++c) {
    bf16x8 a = *(const bf16x8*)&sq[fr * 64 + c * 32 + quad * 8];          // q[h=fr][k]
    bf16x8 b = *(const bf16x8*)&sq[1024 + fr * 64 + c * 32 + quad * 8];   // k[g=fr][k]
    sc = __builtin_amdgcn_mfma_f32_16x16x32_bf16(a, b, sc, 0, 0, 0);
  }

  // softmax over g (row h = quad*4+r lives across the 16 lanes of a quad)
#pragma unroll
  for (int r = 0; r < 4; ++r) {
    float s = sc[r] * 0.03125f;       // 1/sqrt(1024)
    float mx = s;
#pragma unroll
    for (int msk = 1; msk < 16; msk <<= 1) mx = fmaxf(mx, __shfl_xor(mx, msk, 64));
    float e = __expf(s - mx);
    float sum = e;
#pragma unroll
    for (int msk = 1; msk < 16; msk <<= 1) sum += __shfl_xor(sum, msk, 64);
    s_w[wave][(quad * 4 + r) * 16 + fr] = e / sum;
  }
  __syncthreads();

  // attn[h][d=lane] = sum_g w[h][g] * v[g][lane]; write into q slot
  float vv[16];
#pragma unroll
  for (int g = 0; g < 16; ++g) vv[g] = __bfloat162float(sq[2048 + g * 64 + lane]);
  const float* wrow = s_w[wave];
#pragma unroll
  for (int h = 0; h < 16; ++h) {
    float o = 0.f;
#pragma unroll
    for (int g4 = 0; g4 < 4; ++g4) {
      f32x4 w4 = *(const f32x4*)&wrow[h * 16 + g4 * 4];
      o += w4.x * vv[g4 * 4 + 0] + w4.y * vv[g4 * 4 + 1] +
           w4.z * vv[g4 * 4 + 2] + w4.w * vv[g4 * 4 + 3];
    }
    grow[h * 64 + lane] = __float2bfloat16(o);
  }
}

extern "C" void kernel_launch(void* const* d_in, const int* in_sizes, int n_in,
                              void* d_out, int out_size, void* d_ws, size_t ws_size,
                              hipStream_t stream) {
  const float* x    = (const float*)d_in[0];   // (4,4096,1024) fp32
  const float* Wqkv = (const float*)d_in[1];   // (3072,1024) fp32
  const float* Wo   = (const float*)d_in[2];   // (1024,1024) fp32
  const float* bo   = (const float*)d_in[3];   // (1024,) fp32
  float* out = (float*)d_out;                  // (4,4096,1024) fp32
  bf16* qkv  = (bf16*)d_ws;                    // 16384 x 3072 bf16 = 96 MiB scratch

  // 1) qkv = bf16(x) @ bf16(Wqkv)^T   (M=16384, N=3072, K=1024), bf16 out to ws
  gemm_nt<float, float, bf16><<<dim3(3072 / 128, 16384 / 128), 256, 0, stream>>>(
      x, Wqkv, nullptr, qkv, 1024, 1024, 1024, 3072);

  // 2) per-token head attention, attn -> q slot (stride 3072)
  attn_heads<<<dim3(16384 / 4), 256, 0, stream>>>(qkv);

  // 3) out = attn @ bf16(Wo)^T + bo   (M=16384, N=1024, K=1024, lda=3072), fp32 out
  gemm_nt<bf16, float, float><<<dim3(1024 / 128, 16384 / 128), 256, 0, stream>>>(
      qkv, Wo, bo, out, 1024, 3072, 1024, 1024);
}

// Round 7
// 376.652 us; speedup vs baseline: 1.1187x; 1.1187x over previous
//
#include <hip/hip_runtime.h>
#include <hip/hip_bf16.h>

using bf16 = __hip_bfloat16;
typedef __attribute__((ext_vector_type(8))) short bf16x8;   // 8 bf16 = 4 VGPRs (MFMA A/B frag)
typedef __attribute__((ext_vector_type(4))) float f32x4;    // MFMA C/D frag

// async global->LDS, 16B per lane; LDS dest = wave-uniform base + lane*16 (m97/m104)
#define GLL(gp, lp) __builtin_amdgcn_global_load_lds( \
    (const __attribute__((address_space(1))) void*)(gp), \
    (__attribute__((address_space(3))) void*)(lp), 16, 0, 0)

__device__ inline short bfbits(float f) {
  union { bf16 h; short s; } u;
  u.h = __float2bfloat16(f);
  return u.s;
}

// Load 8 contiguous fp32 at fully-formed pointer, return bf16x8.
__device__ inline bf16x8 ldcvt(const float* __restrict__ g) {
  const float4 f0 = *(const float4*)(g);
  const float4 f1 = *(const float4*)(g + 4);
  union { short s[8]; bf16x8 v; } u;
  u.s[0] = bfbits(f0.x); u.s[1] = bfbits(f0.y); u.s[2] = bfbits(f0.z); u.s[3] = bfbits(f0.w);
  u.s[4] = bfbits(f1.x); u.s[5] = bfbits(f1.y); u.s[6] = bfbits(f1.z); u.s[7] = bfbits(f1.w);
  return u.v;
}

__device__ inline void store_c(float* C, size_t idx, float v) { C[idx] = v; }
__device__ inline void store_c(bf16*  C, size_t idx, float v) { C[idx] = __float2bfloat16(v); }

// elementwise fp32 -> bf16, 8 elems/thread
__global__ __launch_bounds__(256)
void f32_to_bf16(const float* __restrict__ src, bf16* __restrict__ dst, int n8) {
  const int i = blockIdx.x * 256 + threadIdx.x;
  if (i < n8) *(bf16x8*)(dst + (size_t)i * 8) = ldcvt(src + (size_t)i * 8);
}

// C[m,n] = sum_k A[m*lda+k] * B[n*ldb+k] (+ bias[n] fp32 if non-null).
// A bf16 (GLL staging); B bf16 (GLL) or fp32 (reg cvt + ds_write); fp32 accum.
// M,N multiples of 128; K multiple of 32. Grid: (N/128, M/128), block 256.
template <typename TB, typename TC>
__global__ __launch_bounds__(256)
void gemm_nt(const bf16* __restrict__ A, const TB* __restrict__ B,
             const float* __restrict__ bias, TC* __restrict__ C,
             int K, int lda, int ldb, int ldc) {
  constexpr bool B_F32 = sizeof(TB) == 4;
  __shared__ __align__(16) bf16 As[128 * 32];
  __shared__ __align__(16) bf16 Bs[128 * 32];
  const int tid  = threadIdx.x;
  const int lane = tid & 63;
  const int wave = tid >> 6;          // 4 waves, 2x2 of 64x64
  const int wm = wave >> 1, wn = wave & 1;
  const int m0 = blockIdx.y * 128;
  const int n0 = blockIdx.x * 128;

  // staging map: wave w covers rows [w*16, w*16+16) of each 64-row chunk;
  // lane l -> row w*16 + (l>>2), col (l&3)*8. LDS bytes = wave*1024 + lane*16
  // (contiguous in lane order — required by GLL wave-uniform-dest semantics).
  const int srow = wave * 16 + (lane >> 2);
  const int scol = (lane & 3) * 8;
  const bf16* gA0 = A + (size_t)(m0 + srow) * lda + scol;
  const bf16* gA1 = A + (size_t)(m0 + 64 + srow) * lda + scol;
  const TB*   gB0 = B + (size_t)(n0 + srow) * ldb + scol;
  const TB*   gB1 = B + (size_t)(n0 + 64 + srow) * ldb + scol;
  bf16* lA0 = &As[(wave * 16) * 32];          // wave-uniform GLL dest
  bf16* lA1 = lA0 + 64 * 32;
  bf16* lB0u = &Bs[(wave * 16) * 32];
  bf16* lB1u = lB0u + 64 * 32;
  bf16* lB0p = &Bs[srow * 32 + scol];         // per-lane dest for ds_write path
  bf16* lB1p = lB0p + 64 * 32;

  const int fr = lane & 15;           // m (A) / n (B) within 16
  const int kq = (lane >> 4) * 8;     // k offset of this lane's 8 contiguous elems
  f32x4 acc[4][4] = {};

  for (int k0 = 0; k0 < K; k0 += 32) {
    bf16x8 b0, b1;
    if constexpr (B_F32) {            // issue fp32 loads before the barrier
      b0 = ldcvt((const float*)gB0 + k0);
      b1 = ldcvt((const float*)gB1 + k0);
    }
    __syncthreads();                  // prev iter's LDS reads done
    GLL(gA0 + k0, lA0);
    GLL(gA1 + k0, lA1);
    if constexpr (B_F32) {
      *(bf16x8*)lB0p = b0;
      *(bf16x8*)lB1p = b1;
    } else {
      GLL((const bf16*)gB0 + k0, lB0u);
      GLL((const bf16*)gB1 + k0, lB1u);
    }
    __syncthreads();                  // drains vmcnt (GLL) + lgkmcnt
    bf16x8 af[4], bfv[4];
#pragma unroll
    for (int t = 0; t < 4; ++t) {
      af[t]  = *(const bf16x8*)&As[(wm * 64 + t * 16 + fr) * 32 + kq];
      bfv[t] = *(const bf16x8*)&Bs[(wn * 64 + t * 16 + fr) * 32 + kq];
    }
#pragma unroll
    for (int i = 0; i < 4; ++i)
#pragma unroll
      for (int j = 0; j < 4; ++j)
        acc[i][j] = __builtin_amdgcn_mfma_f32_16x16x32_bf16(af[i], bfv[j], acc[i][j], 0, 0, 0);
  }

  // C/D layout (verified m89/m91): col = lane&15, row = (lane>>4)*4 + r
  const int rq  = (lane >> 4) * 4;
  const int col = lane & 15;
#pragma unroll
  for (int j = 0; j < 4; ++j) {
    const int cn = n0 + wn * 64 + j * 16 + col;
    const float bv = bias ? bias[cn] : 0.0f;
#pragma unroll
    for (int i = 0; i < 4; ++i) {
      const int cm = m0 + wm * 64 + i * 16 + rq;
#pragma unroll
      for (int r = 0; r < 4; ++r)
        store_c(C, (size_t)(cm + r) * ldc + cn, acc[i][j][r] + bv);
    }
  }
}

// Per-token head-attention on the bf16 qkv workspace.
// qkv row = [q(16x64) | k(16x64) | v(16x64)]. One wave per token. attn -> q slot.
__global__ __launch_bounds__(256)
void attn_heads(bf16* __restrict__ qkv) {
  __shared__ __align__(16) bf16  s_qkv[4][3072];
  __shared__ __align__(16) float s_w[4][256];
  const int lane = threadIdx.x & 63;
  const int wave = threadIdx.x >> 6;
  const size_t tok = (size_t)blockIdx.x * 4 + wave;
  bf16* grow = qkv + tok * 3072;

#pragma unroll
  for (int i = 0; i < 6; ++i) {
    const int off = (i * 64 + lane) * 8;
    *(uint4*)(&s_qkv[wave][off]) = *(const uint4*)(&grow[off]);
  }
  __syncthreads();

  const bf16* sq = s_qkv[wave];
  const int fr   = lane & 15;
  const int quad = lane >> 4;

  // scores = q @ k^T via 2 MFMAs (K=64 -> 2 chunks of 32)
  f32x4 sc = {0.f, 0.f, 0.f, 0.f};
#pragma unroll
  for (int c = 0; c < 2; ++c) {
    bf16x8 a = *(const bf16x8*)&sq[fr * 64 + c * 32 + quad * 8];          // q[h=fr][k]
    bf16x8 b = *(const bf16x8*)&sq[1024 + fr * 64 + c * 32 + quad * 8];   // k[g=fr][k]
    sc = __builtin_amdgcn_mfma_f32_16x16x32_bf16(a, b, sc, 0, 0, 0);
  }

  // softmax over g (row h = quad*4+r lives across the 16 lanes of a quad)
#pragma unroll
  for (int r = 0; r < 4; ++r) {
    float s = sc[r] * 0.03125f;       // 1/sqrt(1024)
    float mx = s;
#pragma unroll
    for (int msk = 1; msk < 16; msk <<= 1) mx = fmaxf(mx, __shfl_xor(mx, msk, 64));
    float e = __expf(s - mx);
    float sum = e;
#pragma unroll
    for (int msk = 1; msk < 16; msk <<= 1) sum += __shfl_xor(sum, msk, 64);
    s_w[wave][(quad * 4 + r) * 16 + fr] = e / sum;
  }
  __syncthreads();

  // attn[h][d=lane] = sum_g w[h][g] * v[g][lane]; write into q slot
  float vv[16];
#pragma unroll
  for (int g = 0; g < 16; ++g) vv[g] = __bfloat162float(sq[2048 + g * 64 + lane]);
  const float* wrow = s_w[wave];
#pragma unroll
  for (int h = 0; h < 16; ++h) {
    float o = 0.f;
#pragma unroll
    for (int g4 = 0; g4 < 4; ++g4) {
      f32x4 w4 = *(const f32x4*)&wrow[h * 16 + g4 * 4];
      o += w4.x * vv[g4 * 4 + 0] + w4.y * vv[g4 * 4 + 1] +
           w4.z * vv[g4 * 4 + 2] + w4.w * vv[g4 * 4 + 3];
    }
    grow[h * 64 + lane] = __float2bfloat16(o);
  }
}

extern "C" void kernel_launch(void* const* d_in, const int* in_sizes, int n_in,
                              void* d_out, int out_size, void* d_ws, size_t ws_size,
                              hipStream_t stream) {
  const float* x    = (const float*)d_in[0];   // (4,4096,1024) fp32, 16.78M elems
  const float* Wqkv = (const float*)d_in[1];   // (3072,1024) fp32, 3.15M elems
  const float* Wo   = (const float*)d_in[2];   // (1024,1024) fp32
  const float* bo   = (const float*)d_in[3];   // (1024,) fp32
  float* out = (float*)d_out;                  // (4,4096,1024) fp32, 64 MiB
  bf16* qkv  = (bf16*)d_ws;                    // 16384 x 3072 bf16 = 96 MiB scratch

  // d_out doubles as pre-GEMM2 scratch: x_bf16 (32 MiB) + Wqkv_bf16 (6 MiB).
  // Both are dead before GEMM2 overwrites d_out with the real output
  // (kernels serialize in-stream).
  bf16* xb    = (bf16*)d_out;                  // 16,777,216 elems
  bf16* wqkvb = xb + 16777216;                 //  3,145,728 elems (ends at 38 MiB)

  // 0) one-time fp32 -> bf16 conversion (cvt paid once, not per tile-reuse)
  f32_to_bf16<<<16777216 / 8 / 256, 256, 0, stream>>>(x, xb, 16777216 / 8);
  f32_to_bf16<<<3145728 / 8 / 256, 256, 0, stream>>>(Wqkv, wqkvb, 3145728 / 8);

  // 1) qkv = xb @ wqkvb^T  (M=16384, N=3072, K=1024), pure bf16 + GLL staging
  gemm_nt<bf16, bf16><<<dim3(3072 / 128, 16384 / 128), 256, 0, stream>>>(
      xb, wqkvb, nullptr, qkv, 1024, 1024, 1024, 3072);

  // 2) per-token head attention, attn -> q slot (stride 3072)
  attn_heads<<<dim3(16384 / 4), 256, 0, stream>>>(qkv);

  // 3) out = attn @ bf16(Wo)^T + bo  (M=16384, N=1024, K=1024, lda=3072)
  //    A via GLL; B = Wo fp32 converted in staging (d_out scratch unsafe here)
  gemm_nt<float, float><<<dim3(1024 / 128, 16384 / 128), 256, 0, stream>>>(
      qkv, Wo, bo, out, 1024, 3072, 1024, 1024);
}